// Round 1
// baseline (1162.691 us; speedup 1.0000x reference)
//
#include <hip/hip_runtime.h>
#include <hip/hip_bf16.h>

#define NN 4096
#define DD 128
#define NS 75
#define TOT (NN * NN)
#define TILE 64
#define KC 64

// ---------------- ws layout (bytes) ----------------
// 0                       : double dist_sum
// 8                       : unsigned long long nz_count
// 16                      : double KL[NS]
// 16 + 8*NS               : double KK[NS]
// 16 + 16*NS              : float sq[NN]
// 16 + 16*NS + 4*NN       : float csig[NS]   (log2e / sigma_s^2)
// 16 + 16*NS + 4*NN + 4*NS: float copt

__global__ void k_rowsq(const float* __restrict__ x, float* __restrict__ sq,
                        double* __restrict__ dsum, unsigned long long* __restrict__ nzc) {
    int tid = blockIdx.x * blockDim.x + threadIdx.x;
    if (tid == 0) { *dsum = 0.0; *nzc = 0ull; }
    if (tid < NN) {
        const float4* row = (const float4*)(x + (size_t)tid * DD);
        float s = 0.f;
#pragma unroll
        for (int i = 0; i < DD / 4; ++i) {
            float4 v = row[i];
            s += v.x * v.x + v.y * v.y + v.z * v.z + v.w * v.w;
        }
        sq[tid] = s;
    }
}

__launch_bounds__(256)
__global__ void k_d2(const float* __restrict__ x, const float* __restrict__ sq,
                     float* __restrict__ d2, double* __restrict__ dsum,
                     unsigned long long* __restrict__ nzc) {
    __shared__ float at[KC][TILE + 4];   // [k][row], padded: compute reads are b128, bank-clean
    __shared__ float bt[KC][TILE + 4];
    __shared__ double red_d[4];
    __shared__ int red_n[4];

    const int tid = threadIdx.x;
    const int tx = tid & 15, ty = tid >> 4;
    const int bi = blockIdx.y, bj = blockIdx.x;
    const int r0 = bi * TILE, c0 = bj * TILE;

    float acc[4][4];
#pragma unroll
    for (int r = 0; r < 4; ++r)
#pragma unroll
        for (int c = 0; c < 4; ++c) acc[r][c] = 0.f;

    for (int kb = 0; kb < DD; kb += KC) {
#pragma unroll
        for (int i = 0; i < 4; ++i) {
            int idx = tid + 256 * i;       // 0..1023
            int row = idx >> 4;            // 0..63
            int k4 = (idx & 15) * 4;       // 0..60
            float4 va = *(const float4*)(x + (size_t)(r0 + row) * DD + kb + k4);
            at[k4 + 0][row] = va.x; at[k4 + 1][row] = va.y;
            at[k4 + 2][row] = va.z; at[k4 + 3][row] = va.w;
            float4 vb = *(const float4*)(x + (size_t)(c0 + row) * DD + kb + k4);
            bt[k4 + 0][row] = vb.x; bt[k4 + 1][row] = vb.y;
            bt[k4 + 2][row] = vb.z; bt[k4 + 3][row] = vb.w;
        }
        __syncthreads();
#pragma unroll 8
        for (int kk = 0; kk < KC; ++kk) {
            float4 a = *(const float4*)&at[kk][ty * 4];
            float4 b = *(const float4*)&bt[kk][tx * 4];
            float av[4] = {a.x, a.y, a.z, a.w};
            float bv[4] = {b.x, b.y, b.z, b.w};
#pragma unroll
            for (int r = 0; r < 4; ++r)
#pragma unroll
                for (int c = 0; c < 4; ++c)
                    acc[r][c] = fmaf(av[r], bv[c], acc[r][c]);
        }
        __syncthreads();
    }

    float sqi[4], sqj[4];
#pragma unroll
    for (int r = 0; r < 4; ++r) sqi[r] = sq[r0 + ty * 4 + r];
#pragma unroll
    for (int c = 0; c < 4; ++c) sqj[c] = sq[c0 + tx * 4 + c];

    double myd = 0.0;
    int myn = 0;
#pragma unroll
    for (int r = 0; r < 4; ++r) {
        float vv[4];
#pragma unroll
        for (int c = 0; c < 4; ++c) {
            float v = sqi[r] + sqj[c] - 2.f * acc[r][c];
            v = fmaxf(v, 0.f);
            vv[c] = v;
            if (v > 0.f) { myd += (double)sqrtf(v); myn++; }
        }
        float4 o = {vv[0], vv[1], vv[2], vv[3]};
        *(float4*)(d2 + (size_t)(r0 + ty * 4 + r) * NN + c0 + tx * 4) = o;
    }

#pragma unroll
    for (int off = 32; off > 0; off >>= 1) {
        myd += __shfl_down(myd, off);
        myn += __shfl_down(myn, off);
    }
    int wave = tid >> 6;
    if ((tid & 63) == 0) { red_d[wave] = myd; red_n[wave] = myn; }
    __syncthreads();
    if (tid == 0) {
        double td = red_d[0] + red_d[1] + red_d[2] + red_d[3];
        int tn = red_n[0] + red_n[1] + red_n[2] + red_n[3];
        atomicAdd(dsum, td);
        atomicAdd(nzc, (unsigned long long)tn);
    }
}

__global__ void k_sigmas(const double* __restrict__ dsum, const unsigned long long* __restrict__ nzc,
                         float* __restrict__ csig, double* __restrict__ KL, double* __restrict__ KK) {
    int t = threadIdx.x;
    float mean = (float)(*dsum / (double)(*nzc));
    float lo = 0.1f * mean;
    float hi = 10.0f * mean;
    float step = (hi - lo) / (float)NS;
    if (t < NS) {
        float s = lo + step * (float)t;
        csig[t] = (float)(1.4426950408889634 / ((double)s * (double)s));
        KL[t] = 0.0;
        KK[t] = 0.0;
    }
}

template <int CH>
__launch_bounds__(256)
__global__ void k_sweep(const float* __restrict__ d2, const float* __restrict__ lk,
                        const float* __restrict__ csig, double* __restrict__ KL,
                        double* __restrict__ KK, int s0) {
    float c[CH];
#pragma unroll
    for (int s = 0; s < CH; ++s) c[s] = csig[s0 + s];
    float akl[CH], akk[CH];
#pragma unroll
    for (int s = 0; s < CH; ++s) { akl[s] = 0.f; akk[s] = 0.f; }

    const int nthreads = gridDim.x * blockDim.x;
    const int t0 = blockIdx.x * blockDim.x + threadIdx.x;
    const float4* d24 = (const float4*)d2;
    const float4* lk4 = (const float4*)lk;
    for (int i = t0; i < TOT / 4; i += nthreads) {
        float4 dv = d24[i];
        float4 lv = lk4[i];
        float dd[4] = {dv.x, dv.y, dv.z, dv.w};
        float ll[4] = {lv.x, lv.y, lv.z, lv.w};
#pragma unroll
        for (int e = 0; e < 4; ++e) {
            float nd = -dd[e];
            float L = ll[e];
#pragma unroll
            for (int s = 0; s < CH; ++s) {
                float K = exp2f(nd * c[s]);
                akl[s] = fmaf(K, L, akl[s]);
                akk[s] = fmaf(K, K, akk[s]);
            }
        }
    }

    __shared__ double shkl[4], shkk[4];
    int lane = threadIdx.x & 63, wave = threadIdx.x >> 6;
    for (int s = 0; s < CH; ++s) {
        float v1 = akl[s], v2 = akk[s];
#pragma unroll
        for (int off = 32; off > 0; off >>= 1) {
            v1 += __shfl_down(v1, off);
            v2 += __shfl_down(v2, off);
        }
        if (lane == 0) { shkl[wave] = (double)v1; shkk[wave] = (double)v2; }
        __syncthreads();
        if (threadIdx.x == 0) {
            atomicAdd(&KL[s0 + s], shkl[0] + shkl[1] + shkl[2] + shkl[3]);
            atomicAdd(&KK[s0 + s], shkk[0] + shkk[1] + shkk[2] + shkk[3]);
        }
        __syncthreads();
    }
}

__global__ void k_argmax(const double* __restrict__ KL, const double* __restrict__ KK,
                         const float* __restrict__ csig, float* __restrict__ copt) {
    if (threadIdx.x == 0 && blockIdx.x == 0) {
        double best = -1.0;
        int bi = 0;
        for (int i = 0; i < NS; ++i) {
            double loss = KL[i] / sqrt(KK[i]);
            if (loss > best) { best = loss; bi = i; }   // strict > keeps FIRST max (jnp.argmax)
        }
        *copt = csig[bi];
    }
}

__launch_bounds__(256)
__global__ void k_final(float* __restrict__ d2, const float* __restrict__ copt) {
    const float c = *copt;
    const float inv_n = 1.0f / (float)NN;
    const int nthreads = gridDim.x * blockDim.x;
    float4* p = (float4*)d2;
    for (int i = blockIdx.x * blockDim.x + threadIdx.x; i < TOT / 4; i += nthreads) {
        float4 v = p[i];
        v.x = exp2f(-v.x * c) * inv_n;
        v.y = exp2f(-v.y * c) * inv_n;
        v.z = exp2f(-v.z * c) * inv_n;
        v.w = exp2f(-v.w * c) * inv_n;
        p[i] = v;
    }
}

extern "C" void kernel_launch(void* const* d_in, const int* in_sizes, int n_in,
                              void* d_out, int out_size, void* d_ws, size_t ws_size,
                              hipStream_t stream) {
    const float* x  = (const float*)d_in[0];
    const float* lk = (const float*)d_in[1];
    float* out = (float*)d_out;   // doubles as the d2 buffer, transformed in place at the end
    char* ws = (char*)d_ws;

    double* dsum = (double*)(ws + 0);
    unsigned long long* nzc = (unsigned long long*)(ws + 8);
    double* KL = (double*)(ws + 16);
    double* KK = (double*)(ws + 16 + 8 * NS);
    float* sqv  = (float*)(ws + 16 + 16 * NS);
    float* csig = (float*)(ws + 16 + 16 * NS + 4 * NN);
    float* copt = (float*)(ws + 16 + 16 * NS + 4 * NN + 4 * NS);

    hipLaunchKernelGGL(k_rowsq, dim3(NN / 256), dim3(256), 0, stream, x, sqv, dsum, nzc);
    hipLaunchKernelGGL(k_d2, dim3(NN / TILE, NN / TILE), dim3(256), 0, stream, x, sqv, out, dsum, nzc);
    hipLaunchKernelGGL(k_sigmas, dim3(1), dim3(128), 0, stream, dsum, nzc, csig, KL, KK);
    hipLaunchKernelGGL((k_sweep<25>), dim3(2048), dim3(256), 0, stream, out, lk, csig, KL, KK, 0);
    hipLaunchKernelGGL((k_sweep<25>), dim3(2048), dim3(256), 0, stream, out, lk, csig, KL, KK, 25);
    hipLaunchKernelGGL((k_sweep<25>), dim3(2048), dim3(256), 0, stream, out, lk, csig, KL, KK, 50);
    hipLaunchKernelGGL(k_argmax, dim3(1), dim3(64), 0, stream, KL, KK, csig, copt);
    hipLaunchKernelGGL(k_final, dim3(2048), dim3(256), 0, stream, out, copt);
}

// Round 2
// 503.146 us; speedup vs baseline: 2.3108x; 2.3108x over previous
//
#include <hip/hip_runtime.h>
#include <hip/hip_bf16.h>

#define NN 4096
#define DD 128
#define NS 75
#define TOT (NN * NN)
#define TILE 64
#define KC 64

// ---------------- ws layout (bytes) ----------------
// 0                       : double dist_sum
// 8                       : unsigned long long nz_count
// 16                      : double KL[NS]
// 16 + 8*NS               : double KK[NS]
// 16 + 16*NS              : float sq[NN]
// 16 + 16*NS + 4*NN       : float csig[NS]   (log2e / sigma_s^2)
// 16 + 16*NS + 4*NN + 4*NS: float copt

__global__ void k_rowsq(const float* __restrict__ x, float* __restrict__ sq,
                        double* __restrict__ dsum, unsigned long long* __restrict__ nzc) {
    int tid = blockIdx.x * blockDim.x + threadIdx.x;
    if (tid == 0) { *dsum = 0.0; *nzc = 0ull; }
    if (tid < NN) {
        const float4* row = (const float4*)(x + (size_t)tid * DD);
        float s = 0.f;
#pragma unroll
        for (int i = 0; i < DD / 4; ++i) {
            float4 v = row[i];
            s += v.x * v.x + v.y * v.y + v.z * v.z + v.w * v.w;
        }
        sq[tid] = s;
    }
}

__launch_bounds__(256)
__global__ void k_d2(const float* __restrict__ x, const float* __restrict__ sq,
                     float* __restrict__ d2, double* __restrict__ dsum,
                     unsigned long long* __restrict__ nzc) {
    __shared__ float at[KC][TILE + 4];   // [k][row], padded: compute reads are b128, bank-clean
    __shared__ float bt[KC][TILE + 4];
    __shared__ double red_d[4];
    __shared__ int red_n[4];

    const int tid = threadIdx.x;
    const int tx = tid & 15, ty = tid >> 4;
    const int bi = blockIdx.y, bj = blockIdx.x;
    const int r0 = bi * TILE, c0 = bj * TILE;

    float acc[4][4];
#pragma unroll
    for (int r = 0; r < 4; ++r)
#pragma unroll
        for (int c = 0; c < 4; ++c) acc[r][c] = 0.f;

    for (int kb = 0; kb < DD; kb += KC) {
#pragma unroll
        for (int i = 0; i < 4; ++i) {
            int idx = tid + 256 * i;       // 0..1023
            int row = idx >> 4;            // 0..63
            int k4 = (idx & 15) * 4;       // 0..60
            float4 va = *(const float4*)(x + (size_t)(r0 + row) * DD + kb + k4);
            at[k4 + 0][row] = va.x; at[k4 + 1][row] = va.y;
            at[k4 + 2][row] = va.z; at[k4 + 3][row] = va.w;
            float4 vb = *(const float4*)(x + (size_t)(c0 + row) * DD + kb + k4);
            bt[k4 + 0][row] = vb.x; bt[k4 + 1][row] = vb.y;
            bt[k4 + 2][row] = vb.z; bt[k4 + 3][row] = vb.w;
        }
        __syncthreads();
#pragma unroll 8
        for (int kk = 0; kk < KC; ++kk) {
            float4 a = *(const float4*)&at[kk][ty * 4];
            float4 b = *(const float4*)&bt[kk][tx * 4];
            float av[4] = {a.x, a.y, a.z, a.w};
            float bv[4] = {b.x, b.y, b.z, b.w};
#pragma unroll
            for (int r = 0; r < 4; ++r)
#pragma unroll
                for (int c = 0; c < 4; ++c)
                    acc[r][c] = fmaf(av[r], bv[c], acc[r][c]);
        }
        __syncthreads();
    }

    float sqi[4], sqj[4];
#pragma unroll
    for (int r = 0; r < 4; ++r) sqi[r] = sq[r0 + ty * 4 + r];
#pragma unroll
    for (int c = 0; c < 4; ++c) sqj[c] = sq[c0 + tx * 4 + c];

    double myd = 0.0;
    int myn = 0;
#pragma unroll
    for (int r = 0; r < 4; ++r) {
        float vv[4];
#pragma unroll
        for (int c = 0; c < 4; ++c) {
            float v = sqi[r] + sqj[c] - 2.f * acc[r][c];
            v = fmaxf(v, 0.f);
            vv[c] = v;
            if (v > 0.f) { myd += (double)sqrtf(v); myn++; }
        }
        float4 o = {vv[0], vv[1], vv[2], vv[3]};
        *(float4*)(d2 + (size_t)(r0 + ty * 4 + r) * NN + c0 + tx * 4) = o;
    }

#pragma unroll
    for (int off = 32; off > 0; off >>= 1) {
        myd += __shfl_down(myd, off);
        myn += __shfl_down(myn, off);
    }
    int wave = tid >> 6;
    if ((tid & 63) == 0) { red_d[wave] = myd; red_n[wave] = myn; }
    __syncthreads();
    if (tid == 0) {
        double td = red_d[0] + red_d[1] + red_d[2] + red_d[3];
        int tn = red_n[0] + red_n[1] + red_n[2] + red_n[3];
        atomicAdd(dsum, td);
        atomicAdd(nzc, (unsigned long long)tn);
    }
}

__global__ void k_sigmas(const double* __restrict__ dsum, const unsigned long long* __restrict__ nzc,
                         float* __restrict__ csig, double* __restrict__ KL, double* __restrict__ KK) {
    int t = threadIdx.x;
    float mean = (float)(*dsum / (double)(*nzc));
    float lo = 0.1f * mean;
    float hi = 10.0f * mean;
    float step = (hi - lo) / (float)NS;
    if (t < NS) {
        float s = lo + step * (float)t;
        csig[t] = (float)(1.4426950408889634 / ((double)s * (double)s));
        KL[t] = 0.0;
        KK[t] = 0.0;
    }
}

template <int CH>
__launch_bounds__(256)
__global__ void k_sweep(const float* __restrict__ d2, const float* __restrict__ lk,
                        const float* __restrict__ csig, double* __restrict__ KL,
                        double* __restrict__ KK, int s0) {
    float c[CH];
#pragma unroll
    for (int s = 0; s < CH; ++s) c[s] = csig[s0 + s];
    float akl[CH], akk[CH];
#pragma unroll
    for (int s = 0; s < CH; ++s) { akl[s] = 0.f; akk[s] = 0.f; }

    const int nthreads = gridDim.x * blockDim.x;
    const int t0 = blockIdx.x * blockDim.x + threadIdx.x;
    const float4* d24 = (const float4*)d2;
    const float4* lk4 = (const float4*)lk;
    for (int i = t0; i < TOT / 4; i += nthreads) {
        float4 dv = d24[i];
        float4 lv = lk4[i];
        float dd[4] = {dv.x, dv.y, dv.z, dv.w};
        float ll[4] = {lv.x, lv.y, lv.z, lv.w};
#pragma unroll
        for (int e = 0; e < 4; ++e) {
            float nd = -dd[e];
            float L = ll[e];
#pragma unroll
            for (int s = 0; s < CH; ++s) {
                float K = exp2f(nd * c[s]);
                akl[s] = fmaf(K, L, akl[s]);
                akk[s] = fmaf(K, K, akk[s]);
            }
        }
    }

    // Block reduction: one barrier, all-sigma LDS partials, runtime indexing
    // only AFTER the hot loop (arrays must stay in VGPRs -> full unroll above).
    __shared__ double part[4][2 * CH];
    const int lane = threadIdx.x & 63, wave = threadIdx.x >> 6;
#pragma unroll
    for (int s = 0; s < CH; ++s) {
        float v1 = akl[s], v2 = akk[s];
#pragma unroll
        for (int off = 32; off > 0; off >>= 1) {
            v1 += __shfl_down(v1, off);
            v2 += __shfl_down(v2, off);
        }
        if (lane == 0) { part[wave][s] = (double)v1; part[wave][CH + s] = (double)v2; }
    }
    __syncthreads();
    const int t = threadIdx.x;
    if (t < 2 * CH) {
        double v = part[0][t] + part[1][t] + part[2][t] + part[3][t];
        if (t < CH) atomicAdd(&KL[s0 + t], v);
        else        atomicAdd(&KK[s0 + t - CH], v);
    }
}

__global__ void k_argmax(const double* __restrict__ KL, const double* __restrict__ KK,
                         const float* __restrict__ csig, float* __restrict__ copt) {
    if (threadIdx.x == 0 && blockIdx.x == 0) {
        double best = -1.0;
        int bi = 0;
        for (int i = 0; i < NS; ++i) {
            double loss = KL[i] / sqrt(KK[i]);
            if (loss > best) { best = loss; bi = i; }   // strict > keeps FIRST max (jnp.argmax)
        }
        *copt = csig[bi];
    }
}

__launch_bounds__(256)
__global__ void k_final(float* __restrict__ d2, const float* __restrict__ copt) {
    const float c = *copt;
    const float inv_n = 1.0f / (float)NN;
    const int nthreads = gridDim.x * blockDim.x;
    float4* p = (float4*)d2;
    for (int i = blockIdx.x * blockDim.x + threadIdx.x; i < TOT / 4; i += nthreads) {
        float4 v = p[i];
        v.x = exp2f(-v.x * c) * inv_n;
        v.y = exp2f(-v.y * c) * inv_n;
        v.z = exp2f(-v.z * c) * inv_n;
        v.w = exp2f(-v.w * c) * inv_n;
        p[i] = v;
    }
}

extern "C" void kernel_launch(void* const* d_in, const int* in_sizes, int n_in,
                              void* d_out, int out_size, void* d_ws, size_t ws_size,
                              hipStream_t stream) {
    const float* x  = (const float*)d_in[0];
    const float* lk = (const float*)d_in[1];
    float* out = (float*)d_out;   // doubles as the d2 buffer, transformed in place at the end
    char* ws = (char*)d_ws;

    double* dsum = (double*)(ws + 0);
    unsigned long long* nzc = (unsigned long long*)(ws + 8);
    double* KL = (double*)(ws + 16);
    double* KK = (double*)(ws + 16 + 8 * NS);
    float* sqv  = (float*)(ws + 16 + 16 * NS);
    float* csig = (float*)(ws + 16 + 16 * NS + 4 * NN);
    float* copt = (float*)(ws + 16 + 16 * NS + 4 * NN + 4 * NS);

    hipLaunchKernelGGL(k_rowsq, dim3(NN / 256), dim3(256), 0, stream, x, sqv, dsum, nzc);
    hipLaunchKernelGGL(k_d2, dim3(NN / TILE, NN / TILE), dim3(256), 0, stream, x, sqv, out, dsum, nzc);
    hipLaunchKernelGGL(k_sigmas, dim3(1), dim3(128), 0, stream, dsum, nzc, csig, KL, KK);
    hipLaunchKernelGGL((k_sweep<25>), dim3(2048), dim3(256), 0, stream, out, lk, csig, KL, KK, 0);
    hipLaunchKernelGGL((k_sweep<25>), dim3(2048), dim3(256), 0, stream, out, lk, csig, KL, KK, 25);
    hipLaunchKernelGGL((k_sweep<25>), dim3(2048), dim3(256), 0, stream, out, lk, csig, KL, KK, 50);
    hipLaunchKernelGGL(k_argmax, dim3(1), dim3(64), 0, stream, KL, KK, csig, copt);
    hipLaunchKernelGGL(k_final, dim3(2048), dim3(256), 0, stream, out, copt);
}

// Round 3
// 267.007 us; speedup vs baseline: 4.3545x; 1.8844x over previous
//
#include <hip/hip_runtime.h>
#include <hip/hip_bf16.h>

#define NN 4096
#define DD 128
#define NS 75
#define TOT (NN * NN)

// k_d2 tiling
#define BT 128
#define KCC 32
#define NBD2 (NN / BT)                      // 32
#define GRID_D2 (NBD2 * (NBD2 + 1) / 2)     // 528

// sweep tiling
#define SB 64
#define NBSW (NN / SB)                      // 64
#define GRID_SW (NBSW * (NBSW + 1) / 2)     // 2080

__device__ __forceinline__ float fexp2(float v) { return __builtin_amdgcn_exp2f(v); }

// linear index -> (bi, bj) with bi <= bj, row-major over upper triangle
__device__ __forceinline__ void tri_decode(int t, int nb, int& bi, int& bj) {
    int b = 0, rem = t;
    while (rem >= nb - b) { rem -= nb - b; ++b; }   // uniform across block -> scalar
    bi = b; bj = b + rem;
}

// ---------------- ws layout (bytes) ----------------
// 0                       : double dist_sum
// 8                       : unsigned long long nz_count
// 16                      : double KL[NS]
// 16 + 8*NS               : double KK[NS]
// 16 + 16*NS              : float sq[NN]
// 16 + 16*NS + 4*NN       : float csig[NS]   (log2e / sigma_s^2)
// 16 + 16*NS + 4*NN + 4*NS: float copt

__global__ void k_rowsq(const float* __restrict__ x, float* __restrict__ sq,
                        double* __restrict__ dsum, unsigned long long* __restrict__ nzc) {
    int tid = blockIdx.x * blockDim.x + threadIdx.x;
    if (tid == 0) { *dsum = 0.0; *nzc = 0ull; }
    if (tid < NN) {
        const float4* row = (const float4*)(x + (size_t)tid * DD);
        float s = 0.f;
#pragma unroll
        for (int i = 0; i < DD / 4; ++i) {
            float4 v = row[i];
            s += v.x * v.x + v.y * v.y + v.z * v.z + v.w * v.w;
        }
        sq[tid] = s;
    }
}

// 128x128 output tile per block, upper-triangle grid, mirrored writes.
// 256 threads: tx = tid&31 (4 cols), ty = tid>>5 (16 rows). 64 FMA / 5 ds_read_b128.
__launch_bounds__(256)
__global__ void k_d2(const float* __restrict__ x, const float* __restrict__ sq,
                     float* __restrict__ d2, double* __restrict__ dsum,
                     unsigned long long* __restrict__ nzc) {
    __shared__ float at[KCC][BT + 4];   // stride 132: 16B-aligned b128 reads, writes 4-way max
    __shared__ float btl[KCC][BT + 4];
    __shared__ double red_d[4];
    __shared__ int red_n[4];

    int bi, bj;
    tri_decode(blockIdx.x, NBD2, bi, bj);
    const int r0 = bi * BT, c0 = bj * BT;
    const int tid = threadIdx.x;
    const int tx = tid & 31;   // col group: 4 cols
    const int ty = tid >> 5;   // row group: 16 rows

    float acc[16][4];
#pragma unroll
    for (int r = 0; r < 16; ++r)
#pragma unroll
        for (int c = 0; c < 4; ++c) acc[r][c] = 0.f;

    for (int kb = 0; kb < DD; kb += KCC) {
#pragma unroll
        for (int i = 0; i < 4; ++i) {
            int idx = tid + 256 * i;       // 0..1023
            int row = idx >> 3;            // 0..127
            int k4 = (idx & 7) * 4;        // 0..28
            float4 va = *(const float4*)(x + (size_t)(r0 + row) * DD + kb + k4);
            at[k4 + 0][row] = va.x; at[k4 + 1][row] = va.y;
            at[k4 + 2][row] = va.z; at[k4 + 3][row] = va.w;
            float4 vb = *(const float4*)(x + (size_t)(c0 + row) * DD + kb + k4);
            btl[k4 + 0][row] = vb.x; btl[k4 + 1][row] = vb.y;
            btl[k4 + 2][row] = vb.z; btl[k4 + 3][row] = vb.w;
        }
        __syncthreads();
#pragma unroll
        for (int kk = 0; kk < KCC; ++kk) {
            float av[16];
            *(float4*)&av[0]  = *(const float4*)&at[kk][ty * 16 + 0];
            *(float4*)&av[4]  = *(const float4*)&at[kk][ty * 16 + 4];
            *(float4*)&av[8]  = *(const float4*)&at[kk][ty * 16 + 8];
            *(float4*)&av[12] = *(const float4*)&at[kk][ty * 16 + 12];
            float4 b4 = *(const float4*)&btl[kk][tx * 4];
            float bv[4] = {b4.x, b4.y, b4.z, b4.w};
#pragma unroll
            for (int r = 0; r < 16; ++r)
#pragma unroll
                for (int c = 0; c < 4; ++c)
                    acc[r][c] = fmaf(av[r], bv[c], acc[r][c]);
        }
        __syncthreads();
    }

    float sqi[16], sqj[4];
#pragma unroll
    for (int r = 0; r < 16; ++r) sqi[r] = sq[r0 + ty * 16 + r];
#pragma unroll
    for (int c = 0; c < 4; ++c) sqj[c] = sq[c0 + tx * 4 + c];

    float myd = 0.f;
    int myn = 0;
#pragma unroll
    for (int r = 0; r < 16; ++r) {
#pragma unroll
        for (int c = 0; c < 4; ++c) {
            float v = fmaxf(sqi[r] + sqj[c] - 2.f * acc[r][c], 0.f);
            acc[r][c] = v;
            if (v > 0.f) { myd += sqrtf(v); ++myn; }
        }
        float4 o = {acc[r][0], acc[r][1], acc[r][2], acc[r][3]};
        *(float4*)(d2 + (size_t)(r0 + ty * 16 + r) * NN + c0 + tx * 4) = o;
    }
    if (bi != bj) {
        // mirror: rows become cols. Per output row: 2 lanes x 64B contiguous.
#pragma unroll
        for (int c = 0; c < 4; ++c) {
            size_t base = (size_t)(c0 + tx * 4 + c) * NN + r0 + ty * 16;
            float4 w0 = {acc[0][c],  acc[1][c],  acc[2][c],  acc[3][c]};
            float4 w1 = {acc[4][c],  acc[5][c],  acc[6][c],  acc[7][c]};
            float4 w2 = {acc[8][c],  acc[9][c],  acc[10][c], acc[11][c]};
            float4 w3 = {acc[12][c], acc[13][c], acc[14][c], acc[15][c]};
            *(float4*)(d2 + base + 0)  = w0;
            *(float4*)(d2 + base + 4)  = w1;
            *(float4*)(d2 + base + 8)  = w2;
            *(float4*)(d2 + base + 12) = w3;
        }
    }

    const int w = (bi == bj) ? 1 : 2;
    double dd_ = (double)myd;
#pragma unroll
    for (int off = 32; off > 0; off >>= 1) {
        dd_ += __shfl_down(dd_, off);
        myn += __shfl_down(myn, off);
    }
    int wave = tid >> 6;
    if ((tid & 63) == 0) { red_d[wave] = dd_; red_n[wave] = myn; }
    __syncthreads();
    if (tid == 0) {
        double td = red_d[0] + red_d[1] + red_d[2] + red_d[3];
        int tn = red_n[0] + red_n[1] + red_n[2] + red_n[3];
        atomicAdd(dsum, td * (double)w);
        atomicAdd(nzc, (unsigned long long)(tn * w));
    }
}

__global__ void k_sigmas(const double* __restrict__ dsum, const unsigned long long* __restrict__ nzc,
                         float* __restrict__ csig, double* __restrict__ KL, double* __restrict__ KK) {
    int t = threadIdx.x;
    float mean = (float)(*dsum / (double)(*nzc));
    float lo = 0.1f * mean;
    float hi = 10.0f * mean;
    float step = (hi - lo) / (float)NS;
    if (t < NS) {
        float s = lo + step * (float)t;
        csig[t] = (float)(1.4426950408889634 / ((double)s * (double)s));
        KL[t] = 0.0;
        KK[t] = 0.0;
    }
}

// Upper-triangle 64x64 blocks; off-diagonal blocks weighted x2 (d2 and lk are
// bitwise symmetric). Per thread: 16 elems x CH sigmas, all in VGPRs.
template <int CH>
__launch_bounds__(256)
__global__ void k_sweep(const float* __restrict__ d2, const float* __restrict__ lk,
                        const float* __restrict__ csig, double* __restrict__ KL,
                        double* __restrict__ KK, int s0) {
    int bi, bj;
    tri_decode(blockIdx.x, NBSW, bi, bj);
    const int r0 = bi * SB, c0 = bj * SB;
    const float w = (bi == bj) ? 1.f : 2.f;

    float c[CH];
#pragma unroll
    for (int s = 0; s < CH; ++s) c[s] = csig[s0 + s];
    float akl[CH], akk[CH];
#pragma unroll
    for (int s = 0; s < CH; ++s) { akl[s] = 0.f; akk[s] = 0.f; }

    const int rr = threadIdx.x >> 4;          // 0..15
    const int c4 = (threadIdx.x & 15) * 4;    // 0..60
#pragma unroll
    for (int it = 0; it < 4; ++it) {
        int row = r0 + rr + 16 * it;
        size_t off = (size_t)row * NN + c0 + c4;
        float4 dv = *(const float4*)(d2 + off);
        float4 lv = *(const float4*)(lk + off);
        float ddv[4] = {dv.x, dv.y, dv.z, dv.w};
        float llv[4] = {lv.x, lv.y, lv.z, lv.w};
#pragma unroll
        for (int e = 0; e < 4; ++e) {
            float nd = -ddv[e];
            float L = llv[e];
#pragma unroll
            for (int s = 0; s < CH; ++s) {
                float K = fexp2(nd * c[s]);
                akl[s] = fmaf(K, L, akl[s]);
                akk[s] = fmaf(K, K, akk[s]);
            }
        }
    }

    __shared__ double part[4][2 * CH];
    const int lane = threadIdx.x & 63, wave = threadIdx.x >> 6;
#pragma unroll
    for (int s = 0; s < CH; ++s) {
        float v1 = akl[s], v2 = akk[s];
#pragma unroll
        for (int off = 32; off > 0; off >>= 1) {
            v1 += __shfl_down(v1, off);
            v2 += __shfl_down(v2, off);
        }
        if (lane == 0) { part[wave][s] = (double)(v1 * w); part[wave][CH + s] = (double)(v2 * w); }
    }
    __syncthreads();
    const int t = threadIdx.x;
    if (t < 2 * CH) {
        double v = part[0][t] + part[1][t] + part[2][t] + part[3][t];
        if (t < CH) atomicAdd(&KL[s0 + t], v);
        else        atomicAdd(&KK[s0 + t - CH], v);
    }
}

__global__ void k_argmax(const double* __restrict__ KL, const double* __restrict__ KK,
                         const float* __restrict__ csig, float* __restrict__ copt) {
    if (threadIdx.x == 0 && blockIdx.x == 0) {
        double best = -1.0;
        int bi = 0;
        for (int i = 0; i < NS; ++i) {
            double loss = KL[i] / sqrt(KK[i]);
            if (loss > best) { best = loss; bi = i; }   // strict > keeps FIRST max (jnp.argmax)
        }
        *copt = csig[bi];
    }
}

__launch_bounds__(256)
__global__ void k_final(float* __restrict__ d2, const float* __restrict__ copt) {
    const float c = *copt;
    const float inv_n = 1.0f / (float)NN;
    const int nthreads = gridDim.x * blockDim.x;
    float4* p = (float4*)d2;
    for (int i = blockIdx.x * blockDim.x + threadIdx.x; i < TOT / 4; i += nthreads) {
        float4 v = p[i];
        v.x = fexp2(-v.x * c) * inv_n;
        v.y = fexp2(-v.y * c) * inv_n;
        v.z = fexp2(-v.z * c) * inv_n;
        v.w = fexp2(-v.w * c) * inv_n;
        p[i] = v;
    }
}

extern "C" void kernel_launch(void* const* d_in, const int* in_sizes, int n_in,
                              void* d_out, int out_size, void* d_ws, size_t ws_size,
                              hipStream_t stream) {
    const float* x  = (const float*)d_in[0];
    const float* lk = (const float*)d_in[1];
    float* out = (float*)d_out;   // doubles as the d2 buffer, transformed in place at the end
    char* ws = (char*)d_ws;

    double* dsum = (double*)(ws + 0);
    unsigned long long* nzc = (unsigned long long*)(ws + 8);
    double* KL = (double*)(ws + 16);
    double* KK = (double*)(ws + 16 + 8 * NS);
    float* sqv  = (float*)(ws + 16 + 16 * NS);
    float* csig = (float*)(ws + 16 + 16 * NS + 4 * NN);
    float* copt = (float*)(ws + 16 + 16 * NS + 4 * NN + 4 * NS);

    hipLaunchKernelGGL(k_rowsq, dim3(NN / 256), dim3(256), 0, stream, x, sqv, dsum, nzc);
    hipLaunchKernelGGL(k_d2, dim3(GRID_D2), dim3(256), 0, stream, x, sqv, out, dsum, nzc);
    hipLaunchKernelGGL(k_sigmas, dim3(1), dim3(128), 0, stream, dsum, nzc, csig, KL, KK);
    hipLaunchKernelGGL((k_sweep<25>), dim3(GRID_SW), dim3(256), 0, stream, out, lk, csig, KL, KK, 0);
    hipLaunchKernelGGL((k_sweep<25>), dim3(GRID_SW), dim3(256), 0, stream, out, lk, csig, KL, KK, 25);
    hipLaunchKernelGGL((k_sweep<25>), dim3(GRID_SW), dim3(256), 0, stream, out, lk, csig, KL, KK, 50);
    hipLaunchKernelGGL(k_argmax, dim3(1), dim3(64), 0, stream, KL, KK, csig, copt);
    hipLaunchKernelGGL(k_final, dim3(2048), dim3(256), 0, stream, out, copt);
}

// Round 4
// 208.905 us; speedup vs baseline: 5.5656x; 1.2781x over previous
//
#include <hip/hip_runtime.h>
#include <hip/hip_bf16.h>

#define NN 4096
#define DD 128
#define NS 75
#define TOT (NN * NN)

// k_d2 tiling
#define BT 128
#define KCC 32
#define NBD2 (NN / BT)                      // 32
#define GRID_D2 (NBD2 * (NBD2 + 1) / 2)     // 528

// sweep tiling
#define SB 64
#define NBSW (NN / SB)                      // 64
#define GRID_SW (NBSW * (NBSW + 1) / 2)     // 2080

__device__ __forceinline__ float fexp2(float v) { return __builtin_amdgcn_exp2f(v); }

// linear index -> (bi, bj) with bi <= bj, row-major over upper triangle
__device__ __forceinline__ void tri_decode(int t, int nb, int& bi, int& bj) {
    int b = 0, rem = t;
    while (rem >= nb - b) { rem -= nb - b; ++b; }   // uniform across block -> scalar
    bi = b; bj = b + rem;
}

// ---------------- ws layout (bytes) ----------------
// 0                       : double dist_sum
// 8                       : unsigned long long nz_count
// 16                      : double KL[NS]
// 16 + 8*NS               : double KK[NS]
// 16 + 16*NS              : float sq[NN]
// 16 + 16*NS + 4*NN       : float csig[NS]   (log2e / sigma_s^2)
// 16 + 16*NS + 4*NN + 4*NS: float copt

__global__ void k_rowsq(const float* __restrict__ x, float* __restrict__ sq,
                        double* __restrict__ dsum, unsigned long long* __restrict__ nzc) {
    int tid = blockIdx.x * blockDim.x + threadIdx.x;
    if (tid == 0) { *dsum = 0.0; *nzc = 0ull; }
    if (tid < NN) {
        const float4* row = (const float4*)(x + (size_t)tid * DD);
        float s = 0.f;
#pragma unroll
        for (int i = 0; i < DD / 4; ++i) {
            float4 v = row[i];
            s += v.x * v.x + v.y * v.y + v.z * v.z + v.w * v.w;
        }
        sq[tid] = s;
    }
}

// 128x128 output tile per block, upper-triangle grid, mirrored writes.
__launch_bounds__(256)
__global__ void k_d2(const float* __restrict__ x, const float* __restrict__ sq,
                     float* __restrict__ d2, double* __restrict__ dsum,
                     unsigned long long* __restrict__ nzc) {
    __shared__ float at[KCC][BT + 4];   // stride 132: 16B-aligned b128 reads, writes 4-way max
    __shared__ float btl[KCC][BT + 4];
    __shared__ double red_d[4];
    __shared__ int red_n[4];

    int bi, bj;
    tri_decode(blockIdx.x, NBD2, bi, bj);
    const int r0 = bi * BT, c0 = bj * BT;
    const int tid = threadIdx.x;
    const int tx = tid & 31;   // col group: 4 cols
    const int ty = tid >> 5;   // row group: 16 rows

    float acc[16][4];
#pragma unroll
    for (int r = 0; r < 16; ++r)
#pragma unroll
        for (int c = 0; c < 4; ++c) acc[r][c] = 0.f;

    for (int kb = 0; kb < DD; kb += KCC) {
#pragma unroll
        for (int i = 0; i < 4; ++i) {
            int idx = tid + 256 * i;       // 0..1023
            int row = idx >> 3;            // 0..127
            int k4 = (idx & 7) * 4;        // 0..28
            float4 va = *(const float4*)(x + (size_t)(r0 + row) * DD + kb + k4);
            at[k4 + 0][row] = va.x; at[k4 + 1][row] = va.y;
            at[k4 + 2][row] = va.z; at[k4 + 3][row] = va.w;
            float4 vb = *(const float4*)(x + (size_t)(c0 + row) * DD + kb + k4);
            btl[k4 + 0][row] = vb.x; btl[k4 + 1][row] = vb.y;
            btl[k4 + 2][row] = vb.z; btl[k4 + 3][row] = vb.w;
        }
        __syncthreads();
#pragma unroll
        for (int kk = 0; kk < KCC; ++kk) {
            float av[16];
            *(float4*)&av[0]  = *(const float4*)&at[kk][ty * 16 + 0];
            *(float4*)&av[4]  = *(const float4*)&at[kk][ty * 16 + 4];
            *(float4*)&av[8]  = *(const float4*)&at[kk][ty * 16 + 8];
            *(float4*)&av[12] = *(const float4*)&at[kk][ty * 16 + 12];
            float4 b4 = *(const float4*)&btl[kk][tx * 4];
            float bv[4] = {b4.x, b4.y, b4.z, b4.w};
#pragma unroll
            for (int r = 0; r < 16; ++r)
#pragma unroll
                for (int c = 0; c < 4; ++c)
                    acc[r][c] = fmaf(av[r], bv[c], acc[r][c]);
        }
        __syncthreads();
    }

    float sqi[16], sqj[4];
#pragma unroll
    for (int r = 0; r < 16; ++r) sqi[r] = sq[r0 + ty * 16 + r];
#pragma unroll
    for (int c = 0; c < 4; ++c) sqj[c] = sq[c0 + tx * 4 + c];

    float myd = 0.f;
    int myn = 0;
#pragma unroll
    for (int r = 0; r < 16; ++r) {
#pragma unroll
        for (int c = 0; c < 4; ++c) {
            float v = fmaxf(sqi[r] + sqj[c] - 2.f * acc[r][c], 0.f);
            acc[r][c] = v;
            if (v > 0.f) { myd += sqrtf(v); ++myn; }
        }
        float4 o = {acc[r][0], acc[r][1], acc[r][2], acc[r][3]};
        *(float4*)(d2 + (size_t)(r0 + ty * 16 + r) * NN + c0 + tx * 4) = o;
    }
    if (bi != bj) {
#pragma unroll
        for (int c = 0; c < 4; ++c) {
            size_t base = (size_t)(c0 + tx * 4 + c) * NN + r0 + ty * 16;
            float4 w0 = {acc[0][c],  acc[1][c],  acc[2][c],  acc[3][c]};
            float4 w1 = {acc[4][c],  acc[5][c],  acc[6][c],  acc[7][c]};
            float4 w2 = {acc[8][c],  acc[9][c],  acc[10][c], acc[11][c]};
            float4 w3 = {acc[12][c], acc[13][c], acc[14][c], acc[15][c]};
            *(float4*)(d2 + base + 0)  = w0;
            *(float4*)(d2 + base + 4)  = w1;
            *(float4*)(d2 + base + 8)  = w2;
            *(float4*)(d2 + base + 12) = w3;
        }
    }

    const int w = (bi == bj) ? 1 : 2;
    double dd_ = (double)myd;
#pragma unroll
    for (int off = 32; off > 0; off >>= 1) {
        dd_ += __shfl_down(dd_, off);
        myn += __shfl_down(myn, off);
    }
    int wave = tid >> 6;
    if ((tid & 63) == 0) { red_d[wave] = dd_; red_n[wave] = myn; }
    __syncthreads();
    if (tid == 0) {
        double td = red_d[0] + red_d[1] + red_d[2] + red_d[3];
        int tn = red_n[0] + red_n[1] + red_n[2] + red_n[3];
        atomicAdd(dsum, td * (double)w);
        atomicAdd(nzc, (unsigned long long)(tn * w));
    }
}

__global__ void k_sigmas(const double* __restrict__ dsum, const unsigned long long* __restrict__ nzc,
                         float* __restrict__ csig, double* __restrict__ KL, double* __restrict__ KK) {
    int t = threadIdx.x;
    float mean = (float)(*dsum / (double)(*nzc));
    float lo = 0.1f * mean;
    float hi = 10.0f * mean;
    float step = (hi - lo) / (float)NS;
    if (t < NS) {
        float s = lo + step * (float)t;
        csig[t] = (float)(1.4426950408889634 / ((double)s * (double)s));
        KL[t] = 0.0;
        KK[t] = 0.0;
    }
}

// Single-pass sweep: each thread loads its 16 (d2,lk) elems into VGPRs ONCE,
// then iterates NCHUNK sigma-chunks of CH over register-resident data.
// Only 2*CH accumulators + CH consts live at a time (#pragma unroll 1).
template <int CH, int NCHUNK>
__launch_bounds__(256, 4)
__global__ void k_sweep_all(const float* __restrict__ d2, const float* __restrict__ lk,
                            const float* __restrict__ csig, double* __restrict__ KL,
                            double* __restrict__ KK) {
    int bi, bj;
    tri_decode(blockIdx.x, NBSW, bi, bj);
    const int r0 = bi * SB, c0 = bj * SB;
    const float w = (bi == bj) ? 1.f : 2.f;

    const int rr = threadIdx.x >> 4;          // 0..15
    const int c4 = (threadIdx.x & 15) * 4;    // 0..60

    float nd[16], ll[16];                      // 32 VGPR, live across all chunks
#pragma unroll
    for (int it = 0; it < 4; ++it) {
        size_t off = (size_t)(r0 + rr + 16 * it) * NN + c0 + c4;
        float4 dv = *(const float4*)(d2 + off);
        float4 lv = *(const float4*)(lk + off);
        nd[it * 4 + 0] = -dv.x; nd[it * 4 + 1] = -dv.y;
        nd[it * 4 + 2] = -dv.z; nd[it * 4 + 3] = -dv.w;
        ll[it * 4 + 0] = lv.x;  ll[it * 4 + 1] = lv.y;
        ll[it * 4 + 2] = lv.z;  ll[it * 4 + 3] = lv.w;
    }

    __shared__ double part[4][2 * CH * NCHUNK];
    const int lane = threadIdx.x & 63, wave = threadIdx.x >> 6;

#pragma unroll 1
    for (int ch = 0; ch < NCHUNK; ++ch) {
        const int s0 = ch * CH;
        float c[CH];
#pragma unroll
        for (int s = 0; s < CH; ++s) c[s] = csig[s0 + s];   // uniform -> scalar loads
        float akl[CH], akk[CH];
#pragma unroll
        for (int s = 0; s < CH; ++s) { akl[s] = 0.f; akk[s] = 0.f; }

#pragma unroll
        for (int e = 0; e < 16; ++e) {
            float ndv = nd[e], L = ll[e];
#pragma unroll
            for (int s = 0; s < CH; ++s) {
                float K = fexp2(ndv * c[s]);
                akl[s] = fmaf(K, L, akl[s]);
                akk[s] = fmaf(K, K, akk[s]);
            }
        }

#pragma unroll
        for (int s = 0; s < CH; ++s) {
            float v1 = akl[s], v2 = akk[s];
#pragma unroll
            for (int off = 32; off > 0; off >>= 1) {
                v1 += __shfl_down(v1, off);
                v2 += __shfl_down(v2, off);
            }
            if (lane == 0) {
                part[wave][2 * s0 + s]      = (double)(v1 * w);
                part[wave][2 * s0 + CH + s] = (double)(v2 * w);
            }
        }
    }
    __syncthreads();
    const int t = threadIdx.x;
    if (t < 2 * CH * NCHUNK) {
        double v = part[0][t] + part[1][t] + part[2][t] + part[3][t];
        const int ch = t / (2 * CH);          // compile-time divisor
        const int r  = t - ch * 2 * CH;
        if (r < CH) atomicAdd(&KL[ch * CH + r], v);
        else        atomicAdd(&KK[ch * CH + r - CH], v);
    }
}

__global__ void k_argmax(const double* __restrict__ KL, const double* __restrict__ KK,
                         const float* __restrict__ csig, float* __restrict__ copt) {
    if (threadIdx.x == 0 && blockIdx.x == 0) {
        double best = -1.0;
        int bi = 0;
        for (int i = 0; i < NS; ++i) {
            double loss = KL[i] / sqrt(KK[i]);
            if (loss > best) { best = loss; bi = i; }   // strict > keeps FIRST max (jnp.argmax)
        }
        *copt = csig[bi];
    }
}

__launch_bounds__(256)
__global__ void k_final(float* __restrict__ d2, const float* __restrict__ copt) {
    const float c = *copt;
    const float inv_n = 1.0f / (float)NN;
    const int nthreads = gridDim.x * blockDim.x;
    float4* p = (float4*)d2;
    for (int i = blockIdx.x * blockDim.x + threadIdx.x; i < TOT / 4; i += nthreads) {
        float4 v = p[i];
        v.x = fexp2(-v.x * c) * inv_n;
        v.y = fexp2(-v.y * c) * inv_n;
        v.z = fexp2(-v.z * c) * inv_n;
        v.w = fexp2(-v.w * c) * inv_n;
        p[i] = v;
    }
}

extern "C" void kernel_launch(void* const* d_in, const int* in_sizes, int n_in,
                              void* d_out, int out_size, void* d_ws, size_t ws_size,
                              hipStream_t stream) {
    const float* x  = (const float*)d_in[0];
    const float* lk = (const float*)d_in[1];
    float* out = (float*)d_out;   // doubles as the d2 buffer, transformed in place at the end
    char* ws = (char*)d_ws;

    double* dsum = (double*)(ws + 0);
    unsigned long long* nzc = (unsigned long long*)(ws + 8);
    double* KL = (double*)(ws + 16);
    double* KK = (double*)(ws + 16 + 8 * NS);
    float* sqv  = (float*)(ws + 16 + 16 * NS);
    float* csig = (float*)(ws + 16 + 16 * NS + 4 * NN);
    float* copt = (float*)(ws + 16 + 16 * NS + 4 * NN + 4 * NS);

    hipLaunchKernelGGL(k_rowsq, dim3(NN / 256), dim3(256), 0, stream, x, sqv, dsum, nzc);
    hipLaunchKernelGGL(k_d2, dim3(GRID_D2), dim3(256), 0, stream, x, sqv, out, dsum, nzc);
    hipLaunchKernelGGL(k_sigmas, dim3(1), dim3(128), 0, stream, dsum, nzc, csig, KL, KK);
    hipLaunchKernelGGL((k_sweep_all<15, 5>), dim3(GRID_SW), dim3(256), 0, stream, out, lk, csig, KL, KK);
    hipLaunchKernelGGL(k_argmax, dim3(1), dim3(64), 0, stream, KL, KK, csig, copt);
    hipLaunchKernelGGL(k_final, dim3(2048), dim3(256), 0, stream, out, copt);
}